// Round 1
// baseline (185.935 us; speedup 1.0000x reference)
//
#include <hip/hip_runtime.h>
#include <hip/hip_bf16.h>
#include <math.h>

typedef float f32x4 __attribute__((ext_vector_type(4)));
typedef short bh8  __attribute__((ext_vector_type(8)));

#define B_   16
#define IC   128
#define OC   256
#define RC   128
#define STY  512
#define KS_  3
#define LL   16384
#define LT   64

// ws layout (bytes)
#define WS_S_OFF   0
#define WS_W_OFF   8192
#define WS_W1_OFF  (8192 + 3145728)

__device__ __forceinline__ unsigned short f2b(float f) {
    union { float f; unsigned int u; } z; z.f = f;
    unsigned int u = z.u;
    return (unsigned short)((u + 0x7fffu + ((u >> 16) & 1u)) >> 16);
}

// ---------------- prologue 1: s[b][i] = style @ (mod_weight*scale).T + bias ----
__global__ void k_style(const float* __restrict__ style, const float* __restrict__ mw,
                        const float* __restrict__ mb, float* __restrict__ s_out) {
    const int b = blockIdx.x, i = threadIdx.x;
    const float4* st = (const float4*)(style + b * STY);
    const float4* w  = (const float4*)(mw + (size_t)i * STY);
    float acc = 0.f;
#pragma unroll 4
    for (int j = 0; j < STY / 4; ++j) {
        float4 a = st[j], c = w[j];
        acc += a.x * c.x + a.y * c.y + a.z * c.z + a.w * c.w;
    }
    s_out[b * IC + i] = acc * 0.044194173824159216f + mb[i];  // 1/sqrt(512)
}

// ---------------- prologue 2: modulated+demodulated bf16 weights ---------------
// wbf[b][o][tap*128 + i]
__global__ void k_modw(const float* __restrict__ cw, const float* __restrict__ s,
                       unsigned short* __restrict__ wbf) {
    const int o = blockIdx.x, b = blockIdx.y, i = threadIdx.x;
    const float sv = s[b * IC + i] * 0.029462782549439476f;  // 1/sqrt(128*9)
    const float w0 = cw[(o * IC + i) * KS_ + 0] * sv;
    const float w1 = cw[(o * IC + i) * KS_ + 1] * sv;
    const float w2 = cw[(o * IC + i) * KS_ + 2] * sv;
    float ss = w0 * w0 + w1 * w1 + w2 * w2;
    for (int off = 32; off; off >>= 1) ss += __shfl_down(ss, off, 64);
    __shared__ float red[2];
    if ((i & 63) == 0) red[i >> 6] = ss;
    __syncthreads();
    const float d = rsqrtf(red[0] + red[1] + 1e-8f);
    unsigned short* dst = wbf + ((size_t)b * OC + o) * 384 + i;
    dst[0]   = f2b(w0 * d);
    dst[128] = f2b(w1 * d);
    dst[256] = f2b(w2 * d);
}

// ---------------- prologue 3: weight-normed 1x1 conv matrix (bf16) -------------
__global__ void k_w1(const float* __restrict__ v, const float* __restrict__ g,
                     unsigned short* __restrict__ w1bf) {
    const int o = blockIdx.x, c = threadIdx.x;
    const float vv = v[o * RC + c];
    float ss = vv * vv;
    for (int off = 32; off; off >>= 1) ss += __shfl_down(ss, off, 64);
    __shared__ float red[2];
    if ((c & 63) == 0) red[c >> 6] = ss;
    __syncthreads();
    w1bf[o * RC + c] = f2b(g[o] * vv * rsqrtf(red[0] + red[1]));
}

// ---------------- main fused kernel -------------------------------------------
// LDS: [0,16896)  xs_t bf16 [66][128] (swizzled)  -> later gs_t bf16 [64][128]
//      [16896, +34816) ys f32 [128][68]
#define YS_OFF 16896

__global__ __launch_bounds__(512, 4) void k_main(
    const float* __restrict__ x, const unsigned short* __restrict__ wbf,
    const unsigned short* __restrict__ w1bf, const float* __restrict__ obias,
    float* __restrict__ out) {
    __shared__ alignas(16) char smem[16896 + 34816];

    const int t = threadIdx.x;
    const int lane = t & 63, wv = t >> 6;
    const int b = blockIdx.y;
    const int l0 = blockIdx.x * LT;

    // ---- stage x tile (fp32 kept in regs for residual; bf16 transposed to LDS)
    const int r = t >> 2, c4 = t & 3;
    const float* xrow = x + ((size_t)b * IC + r) * LL + l0 + c4 * 16;
    float4 xv[4];
#pragma unroll
    for (int q = 0; q < 4; ++q) xv[q] = ((const float4*)xrow)[q];

    if (t < IC) {  // halo columns l0-1 (row 0) and l0+64 (row 65)
        float lf = (l0 > 0) ? x[((size_t)b * IC + t) * LL + l0 - 1] : 0.f;
        float rt = (l0 + LT < LL) ? x[((size_t)b * IC + t) * LL + l0 + LT] : 0.f;
        *(unsigned short*)(smem + 0 * 256 + ((t * 2) ^ ((0 & 7) << 4)))  = f2b(lf);
        *(unsigned short*)(smem + 65 * 256 + ((t * 2) ^ ((65 & 7) << 4))) = f2b(rt);
    }
#pragma unroll
    for (int q = 0; q < 4; ++q) {
#pragma unroll
        for (int e = 0; e < 4; ++e) {
            const int n = c4 * 16 + q * 4 + e;
            const int lr = n + 1;
            const float v = (e == 0) ? xv[q].x : (e == 1) ? xv[q].y : (e == 2) ? xv[q].z : xv[q].w;
            *(unsigned short*)(smem + lr * 256 + ((r * 2) ^ ((lr & 7) << 4))) = f2b(v);
        }
    }
    __syncthreads();

    // ---- conv: M-tiles [16w,16w+16) (xa) and [128+16w,+16) (xb), N=64, K=384
    f32x4 acc[2][4];
#pragma unroll
    for (int m = 0; m < 2; ++m)
#pragma unroll
        for (int nt = 0; nt < 4; ++nt) acc[m][nt] = (f32x4){0.f, 0.f, 0.f, 0.f};

    const int lm = lane & 15, kg = lane >> 4;
    const unsigned short* wa = wbf + ((size_t)b * OC + wv * 16 + lm) * 384 + kg * 8;
    const unsigned short* wb = wbf + ((size_t)b * OC + 128 + wv * 16 + lm) * 384 + kg * 8;

#pragma unroll
    for (int kc = 0; kc < 12; ++kc) {
        const int tap = kc >> 2;
        const int icb = (kc & 3) * 32;
        const int koff = tap * 128 + icb;
        const bh8 a0 = *(const bh8*)(wa + koff);
        const bh8 a1 = *(const bh8*)(wb + koff);
#pragma unroll
        for (int nt = 0; nt < 4; ++nt) {
            const int lr = nt * 16 + lm + tap;
            const bh8 bf = *(const bh8*)(smem + lr * 256 + (((icb + kg * 8) * 2) ^ ((lr & 7) << 4)));
            acc[0][nt] = __builtin_amdgcn_mfma_f32_16x16x32_bf16(a0, bf, acc[0][nt], 0, 0, 0);
            acc[1][nt] = __builtin_amdgcn_mfma_f32_16x16x32_bf16(a1, bf, acc[1][nt], 0, 0, 0);
        }
    }

    // ---- gated tanh-sigmoid, fully in registers (xa/xb pair is wave-local)
    unsigned short gb[4][4];
#pragma unroll
    for (int nt = 0; nt < 4; ++nt) {
#pragma unroll
        for (int j = 0; j < 4; ++j) {
            const float xa = acc[0][nt][j], xb = acc[1][nt][j];
            const float th = 1.f - 2.f * __builtin_amdgcn_rcpf(__expf(2.f * xa) + 1.f);
            const float sg = __builtin_amdgcn_rcpf(1.f + __expf(-xb));
            gb[nt][j] = f2b(th * sg);
        }
    }
    __syncthreads();  // all xs_t reads done before overlay

    // write g transposed: gs_t[n][c], same swizzle
#pragma unroll
    for (int nt = 0; nt < 4; ++nt) {
        const int n = nt * 16 + lm;
#pragma unroll
        for (int j = 0; j < 4; ++j) {
            const int c = wv * 16 + kg * 4 + j;
            *(unsigned short*)(smem + n * 256 + ((c * 2) ^ ((n & 7) << 4))) = gb[nt][j];
        }
    }
    __syncthreads();

    // ---- 1x1 conv: y[128][64] = w1[128][128] @ g
    f32x4 acc2[4];
#pragma unroll
    for (int nt = 0; nt < 4; ++nt) acc2[nt] = (f32x4){0.f, 0.f, 0.f, 0.f};
    const unsigned short* w1p = w1bf + (wv * 16 + lm) * RC + kg * 8;
#pragma unroll
    for (int kc = 0; kc < 4; ++kc) {
        const bh8 a0 = *(const bh8*)(w1p + kc * 32);
#pragma unroll
        for (int nt = 0; nt < 4; ++nt) {
            const int n = nt * 16 + lm;
            const bh8 bf = *(const bh8*)(smem + n * 256 + (((kc * 32 + kg * 8) * 2) ^ ((n & 7) << 4)));
            acc2[nt] = __builtin_amdgcn_mfma_f32_16x16x32_bf16(a0, bf, acc2[nt], 0, 0, 0);
        }
    }

    // ---- ys via LDS for coalesced epilogue
    float* ys = (float*)(smem + YS_OFF);
#pragma unroll
    for (int nt = 0; nt < 4; ++nt) {
        const int n = nt * 16 + lm;
#pragma unroll
        for (int j = 0; j < 4; ++j) {
            const int o2 = wv * 16 + kg * 4 + j;
            ys[o2 * 68 + n] = acc2[nt][j];
        }
    }
    __syncthreads();

    // ---- epilogue: out = (y + bias + x) * sqrt(0.5)
    const float bias = obias[r];
    float* orow = out + ((size_t)b * IC + r) * LL + l0 + c4 * 16;
#pragma unroll
    for (int q = 0; q < 4; ++q) {
        const float4 yv = *(const float4*)(ys + r * 68 + c4 * 16 + q * 4);
        float4 ov;
        ov.x = (yv.x + bias + xv[q].x) * 0.70710678118654752f;
        ov.y = (yv.y + bias + xv[q].y) * 0.70710678118654752f;
        ov.z = (yv.z + bias + xv[q].z) * 0.70710678118654752f;
        ov.w = (yv.w + bias + xv[q].w) * 0.70710678118654752f;
        ((float4*)orow)[q] = ov;
    }
}

extern "C" void kernel_launch(void* const* d_in, const int* in_sizes, int n_in,
                              void* d_out, int out_size, void* d_ws, size_t ws_size,
                              hipStream_t stream) {
    (void)in_sizes; (void)n_in; (void)out_size; (void)ws_size;
    const float* x        = (const float*)d_in[0];
    const float* style    = (const float*)d_in[1];
    const float* conv_w   = (const float*)d_in[2];
    const float* mod_w    = (const float*)d_in[3];
    const float* mod_b    = (const float*)d_in[4];
    const float* out_v    = (const float*)d_in[5];
    const float* out_g    = (const float*)d_in[6];
    const float* out_bias = (const float*)d_in[7];
    float* out = (float*)d_out;

    float* s_buf = (float*)((char*)d_ws + WS_S_OFF);
    unsigned short* wbf  = (unsigned short*)((char*)d_ws + WS_W_OFF);
    unsigned short* w1bf = (unsigned short*)((char*)d_ws + WS_W1_OFF);

    k_style<<<dim3(B_), 128, 0, stream>>>(style, mod_w, mod_b, s_buf);
    k_modw<<<dim3(OC, B_), 128, 0, stream>>>(conv_w, s_buf, wbf);
    k_w1<<<dim3(RC), 128, 0, stream>>>(out_v, out_g, w1bf);
    k_main<<<dim3(LL / LT, B_), 512, 0, stream>>>(x, wbf, w1bf, out_bias, out);
}